// Round 4
// baseline (112.971 us; speedup 1.0000x reference)
//
#include <hip/hip_runtime.h>
#include <math.h>

// x [32,1024,64,64] f32, w [1,1024], b [1], mode scalar int.
typedef float v4f __attribute__((ext_vector_type(4)));  // native vec: OK for nontemporal builtin

constexpr int B_ = 32;
constexpr int C_ = 1024;
constexpr int HW = 64 * 64;            // 4096 spatial per batch (1024 float4)
constexpr int NSPATIAL = B_ * HW;      // 131072
constexpr int BLOCK = 512;             // 8 waves
constexpr int WAVES = 8;
constexpr int CPW = C_ / WAVES;        // 128 channels per wave
constexpr int PX_PER_BLOCK = 256;      // 64 v4f per block, shared by all waves
constexpr int NBLOCKS = NSPATIAL / PX_PER_BLOCK;  // 512

// Fused: dot over all 1024 channels (split 128/wave across 8 waves),
// LDS-combine, bias + sigmoid + softplus - z*y, block-reduce, and the
// last-arriving block performs the final deterministic 512-way reduce.
__global__ __launch_bounds__(BLOCK) void k_main(
    const v4f* __restrict__ x4, const v4f* __restrict__ w4g,
    const float* __restrict__ bias, const int* __restrict__ mode,
    float* __restrict__ blocksum, int* __restrict__ counter,
    float* __restrict__ out) {
    __shared__ v4f  w4[C_ / 4];        // 1024 weights (4 KB)
    __shared__ v4f  red[BLOCK];        // 8 KB
    __shared__ float fred[NBLOCKS];    // 2 KB, final reduce
    __shared__ int   s_last;

    const int t    = threadIdx.x;
    const int wv   = t >> 6;           // wave 0..7 -> channel eighth
    const int lane = t & 63;

    if (t < C_ / 4) w4[t] = w4g[t];
    __syncthreads();

    const int blk = blockIdx.x;        // 0..511
    const int b   = blk >> 4;          // 16 tiles per batch image
    const int hw4 = (blk & 15) * 64 + lane;  // v4f index in 4096-px plane

    const v4f* p = x4 + ((size_t)(b * C_ + wv * CPW)) * (HW / 4) + hw4;

    v4f acc = (v4f)(0.f);
    #pragma unroll 4
    for (int kk = 0; kk < CPW / 4; ++kk) {     // 32 iters x 4 loads
        v4f wc = w4[(wv * CPW) / 4 + kk];
        v4f v0 = __builtin_nontemporal_load(&p[(size_t)(4 * kk + 0) * (HW / 4)]);
        v4f v1 = __builtin_nontemporal_load(&p[(size_t)(4 * kk + 1) * (HW / 4)]);
        v4f v2 = __builtin_nontemporal_load(&p[(size_t)(4 * kk + 2) * (HW / 4)]);
        v4f v3 = __builtin_nontemporal_load(&p[(size_t)(4 * kk + 3) * (HW / 4)]);
        acc += wc.x * v0 + wc.y * v1 + wc.z * v2 + wc.w * v3;
    }

    red[t] = acc;
    __syncthreads();

    if (t < 64) {
        v4f s = red[t];
        #pragma unroll
        for (int k = 1; k < WAVES; ++k) s += red[t + 64 * k];
        const float bb = bias[0];
        const float y  = (float)mode[0];
        float logit[4] = {s.x, s.y, s.z, s.w};
        float local = 0.f;
        #pragma unroll
        for (int j = 0; j < 4; ++j) {
            float lg = logit[j] + bb;
            float z  = 1.f / (1.f + __expf(-lg));   // sigmoid
            local   += log1pf(__expf(z)) - z * y;   // softplus(z) - z*y
        }
        #pragma unroll
        for (int off = 32; off > 0; off >>= 1)
            local += __shfl_down(local, off, 64);
        if (lane == 0) blocksum[blk] = local;
    }

    // last-block-done: the block that gets ticket NBLOCKS-1 does the final sum
    if (t == 0) {
        __threadfence();                       // release blocksum[blk]
        int ticket = atomicAdd(counter, 1);    // device-scope by default
        s_last = (ticket == NBLOCKS - 1) ? 1 : 0;
    }
    __syncthreads();
    if (s_last) {
        __threadfence();                       // acquire all blocksum writes
        fred[t] = blocksum[t];                 // BLOCK == NBLOCKS == 512
        __syncthreads();
        for (int off = NBLOCKS / 2; off > 0; off >>= 1) {
            if (t < off) fred[t] += fred[t + off];
            __syncthreads();
        }
        if (t == 0) out[0] = fred[0] / (float)NSPATIAL;
    }
}

extern "C" void kernel_launch(void* const* d_in, const int* in_sizes, int n_in,
                              void* d_out, int out_size, void* d_ws, size_t ws_size,
                              hipStream_t stream) {
    const v4f*   x4  = (const v4f*)d_in[0];
    const v4f*   w4g = (const v4f*)d_in[1];
    const float* bia = (const float*)d_in[2];
    const int*   mod = (const int*)d_in[3];
    float* out = (float*)d_out;

    float* blocksum = (float*)d_ws;                         // 512 floats
    int*   counter  = (int*)((char*)d_ws + NBLOCKS * sizeof(float));

    (void)hipMemsetAsync(counter, 0, sizeof(int), stream);  // graph-capturable
    k_main<<<NBLOCKS, BLOCK, 0, stream>>>(x4, w4g, bia, mod, blocksum, counter, out);
}